// Round 7
// baseline (320.204 us; speedup 1.0000x reference)
//
#include <hip/hip_runtime.h>

#define BB    16384
#define NF    24
#define CARDN 10000
#define DD    16
#define NI    276      // 24*23/2
#define H1N   128
#define H2N   64
#define SB    4        // samples per block
#define PSTR  5        // pairsT [p][s] stride
#define GRP   12       // rows per fetch group (2 groups = 24 rows)
#define ROWF  368      // floats per staged row (23 chunks x 16; diagonal skipped)
#define GF    (GRP * ROWF)   // 4416 floats per group buffer
#define F4PG  1104     // float4 per group fetch (12 rows x 92)

// ---------------------------------------------------------------------------
// R7: coalesced row-burst gather + tri-buffered software pipeline.
//  - stage t (t=0..7): global_load_lds 12 rows E[r, x[s,r], :] (minus the
//    diagonal 64B chunk) as ~1.4KB bursts into buf[t%3]; THEN compute the
//    pair-dot set enabled by stages t-1/t-2; THEN one __syncthreads (its
//    vmcnt(0) drain = completion guarantee for buf[t%3]).
//    odd t: 66 pairs with i,j<12 (sample t>>1); even t>=2: 210 cross+G1
//    pairs (sample (t>>1)-1).  Fetch of stage t flies during compute+barrier
//    of stage t-1 -> HBM pipeline never drains (R4's flaw fixed).
//  - then R5-proven tile MLP: wave-per-sample, GEMM1 2cols/thread,
//    GEMM2+3 in registers with full-wave shuffle reduce.
//  LDS 62.6 KB -> 2 blocks/CU; 4096 blocks -> 8 staggered generations.
// ---------------------------------------------------------------------------

__device__ __forceinline__ void gll16(const float* g, float* l) {
    __builtin_amdgcn_global_load_lds(
        (const __attribute__((address_space(1))) unsigned int*)(g),
        (__attribute__((address_space(3))) unsigned int*)(l),
        16, 0, 0);
}

__global__ __launch_bounds__(256, 2) void fanfm_pipe_kernel(
    const int* __restrict__ x, const float* __restrict__ E,
    const float* __restrict__ Wlin, const float* __restrict__ blin,
    const float* __restrict__ W1, const float* __restrict__ b1,
    const float* __restrict__ W2, const float* __restrict__ b2,
    const float* __restrict__ W3, const float* __restrict__ b3,
    float* __restrict__ out)
{
    __shared__ float buf[3 * GF];        // 52992 B  row-group tri-buffer
    __shared__ float pairsT[NI * PSTR];  //  5520 B  [p][s]
    __shared__ float h1T[H1N * PSTR];    //  2560 B  [c][s]
    __shared__ int   xs[SB * NF];        //   384 B
    __shared__ int   ptab[NI];           //  1104 B  packed (i | j<<5 | p<<10)
    __shared__ float lin_s[SB];          //    16 B
    __shared__ int   cnt01[2];

    const int tid = threadIdx.x;
    const int b0  = blockIdx.x * SB;
    const int wb  = tid & ~63;           // wave base (uniform per wave)

    // --- init: x tile + segment counters ---
    if (tid < SB * NF) xs[tid] = x[b0 * NF + tid];
    if (tid < 2) cnt01[tid] = (tid == 0) ? 0 : 66;
    __syncthreads();

    // --- build pair table (NI=276 > 256 -> strided loop!) ---
    for (int pp = tid; pp < NI; pp += 256) {
        int i = 0, rem = pp, cnt = NF - 1;
        while (rem >= cnt) { rem -= cnt; --cnt; ++i; }
        int j = i + 1 + rem;
        int seg = (j < GRP) ? 0 : 1;       // j<12 implies i<12 (i<j)
        int slot = atomicAdd(&cnt01[seg], 1);
        ptab[slot] = i | (j << 5) | (pp << 10);
    }
    __syncthreads();

    // --- linear term (overlaps with pipeline fetches) ---
    if (tid < SB) {
        float l = blin[0] + b3[0];
        #pragma unroll
        for (int f = 0; f < NF; ++f) l += Wlin[f * CARDN + xs[tid * NF + f]];
        lin_s[tid] = l;
    }

    // --- pipelined gather: 9 stages (8 fetch, computes at t>=1) ---
    for (int t = 0; t <= 2 * SB; ++t) {
        // issue fetch for stage t (group g of sample s) into buf[t%3]
        if (t < 2 * SB) {
            const int g = t & 1;
            const int s = t >> 1;
            float* bt = buf + (t % 3) * GF;
            #pragma unroll
            for (int k = 0; k < 5; ++k) {
                int idx = k * 256 + tid;
                if (idx < F4PG) {
                    int r   = idx / 92;        // local row 0..11
                    int f4i = idx - r * 92;    // 0..91
                    int c   = f4i >> 2;        // chunk 0..22
                    int q   = f4i & 3;
                    int rg  = g * GRP + r;
                    int j   = c + (c >= rg ? 1 : 0);   // skip diagonal col
                    const float* src = E
                        + ((size_t)rg * CARDN + xs[s * NF + rg]) * (NF * DD)
                        + j * DD + q * 4;
                    gll16(src, bt + (k * 256 + wb) * 4);
                }
            }
        }
        // compute the pair set whose buffers completed at earlier barriers
        if (t >= 1) {
            int segb, segn, s, bA, bB;
            if (t & 1) { s = t >> 1;       segb = 0;  segn = 66;
                         bA = (t - 1) % 3; bB = bA; }
            else       { s = (t >> 1) - 1; segb = 66; segn = 210;
                         bA = (t - 2) % 3; bB = (t - 1) % 3; }
            if (tid < segn) {
                int e = ptab[segb + tid];
                int i = e & 31, j = (e >> 5) & 31, p = e >> 10;
                // a = row i chunk for col j (pos j-1); c = row j chunk col i (pos i)
                const float4* ra = (const float4*)(buf
                    + (i < GRP ? bA : bB) * GF + (i % GRP) * ROWF + (j - 1) * DD);
                const float4* rc = (const float4*)(buf
                    + (j < GRP ? bA : bB) * GF + (j % GRP) * ROWF + i * DD);
                float4 a0 = ra[0], a1 = ra[1], a2 = ra[2], a3 = ra[3];
                float4 c0 = rc[0], c1 = rc[1], c2 = rc[2], c3 = rc[3];
                float d =
                    a0.x*c0.x + a0.y*c0.y + a0.z*c0.z + a0.w*c0.w +
                    a1.x*c1.x + a1.y*c1.y + a1.z*c1.z + a1.w*c1.w +
                    a2.x*c2.x + a2.y*c2.y + a2.z*c2.z + a2.w*c2.w +
                    a3.x*c3.x + a3.y*c3.y + a3.z*c3.z + a3.w*c3.w;
                pairsT[p * PSTR + s] = d;
            }
        }
        __syncthreads();   // drains this wave's loads -> buf[t%3] complete
    }

    // --- GEMM1: thread = 2 cols x 1 sample (wave = sample) ---
    const int c2 = tid & 63;     // cols 2*c2, 2*c2+1
    const int sM = tid >> 6;     // 0..3
    {
        float a0 = 0.f, a1 = 0.f;
        #pragma unroll 4
        for (int p = 0; p < NI; ++p) {
            float pr = pairsT[p * PSTR + sM];
            float2 w = *(const float2*)(W1 + p * H1N + c2 * 2);
            a0 = fmaf(pr, w.x, a0);
            a1 = fmaf(pr, w.y, a1);
        }
        h1T[(c2 * 2 + 0) * PSTR + sM] = fmaxf(a0 + b1[c2 * 2 + 0], 0.f);
        h1T[(c2 * 2 + 1) * PSTR + sM] = fmaxf(a1 + b1[c2 * 2 + 1], 0.f);
    }
    __syncthreads();

    // --- GEMM2 (in regs) + GEMM3 via full-wave shuffle reduce ---
    {
        float acc = 0.f;
        #pragma unroll 4
        for (int p = 0; p < H1N; ++p)
            acc = fmaf(h1T[p * PSTR + sM], W2[p * H2N + c2], acc);
        float r = fmaxf(acc + b2[c2], 0.f) * W3[c2];
        r += __shfl_xor(r, 1);
        r += __shfl_xor(r, 2);
        r += __shfl_xor(r, 4);
        r += __shfl_xor(r, 8);
        r += __shfl_xor(r, 16);
        r += __shfl_xor(r, 32);
        if (c2 == 0) out[b0 + sM] = r + lin_s[sM];
    }
}

extern "C" void kernel_launch(void* const* d_in, const int* in_sizes, int n_in,
                              void* d_out, int out_size, void* d_ws, size_t ws_size,
                              hipStream_t stream) {
    const int*   x    = (const int*)  d_in[0];
    const float* E    = (const float*)d_in[1];
    const float* Wlin = (const float*)d_in[2];
    const float* blin = (const float*)d_in[3];
    const float* W1   = (const float*)d_in[4];
    const float* b1   = (const float*)d_in[5];
    const float* W2   = (const float*)d_in[6];
    const float* b2   = (const float*)d_in[7];
    const float* W3   = (const float*)d_in[8];
    const float* b3   = (const float*)d_in[9];
    float* out = (float*)d_out;
    (void)d_ws; (void)ws_size; (void)in_sizes; (void)n_in; (void)out_size;

    fanfm_pipe_kernel<<<BB / SB, 256, 0, stream>>>(
        x, E, Wlin, blin, W1, b1, W2, b2, W3, b3, out);
}

// Round 8
// 202.061 us; speedup vs baseline: 1.5847x; 1.5847x over previous
//
#include <hip/hip_runtime.h>

#define BB     16384
#define NF     24
#define CARDN  10000
#define DD     16
#define NI     276            // 24*23/2
#define H1N    128
#define H2N    64
#define SB     16             // samples per block
#define NT     576            // 9 waves
#define CH_F4  5              // chunk stride in float4 (4 data + 1 pad) -> 20 words % 32 = 20
#define ROW_F4 121            // row stride in float4 (24*5 + 1)         -> 484 words % 32 = 4
#define BUF_F4 (NF * ROW_F4)  // 2904 float4 per sample buffer
#define PSTR   17             // pairsT [p][s] stride

// ---------------------------------------------------------------------------
// R8: coalesced row-burst gather, register-staged, double-buffered, padded LDS.
//  per stage (1 sample): issue 4 float4 global loads/thread for sample t+1
//  (contiguous 1.5KB row bursts) -> compute sample t's 276 pair dots from the
//  PADDED LDS buffer (chunk stride 20 words, row stride 484 words: a-reads
//  step 20 mod 32, c-reads step 4 mod 32 -> all 8 bank-quads, <=3-way
//  conflicts; R4/R7's fatal 64B-stride 12-way conflict eliminated) ->
//  vmcnt-wait own loads (hidden under compute) -> ds_write buf[(t+1)&1] ->
//  ONE barrier. Loads stay wave-private so no vmcnt(0)-drain coupling.
//  Then the R5-proven tile MLP. 119KB LDS -> 1 block/CU, 4 generations.
// ---------------------------------------------------------------------------
__global__ __launch_bounds__(NT, 1) void fanfm_r8_kernel(
    const int* __restrict__ x, const float* __restrict__ E,
    const float* __restrict__ Wlin, const float* __restrict__ blin,
    const float* __restrict__ W1, const float* __restrict__ b1,
    const float* __restrict__ W2, const float* __restrict__ b2,
    const float* __restrict__ W3, const float* __restrict__ b3,
    float* __restrict__ out)
{
    __shared__ float4 buf[2 * BUF_F4];     // 92928 B  double-buffered sample
    __shared__ float  pairsT[NI * PSTR];   // 18768 B  [p][s]
    __shared__ float  h1T[H1N * PSTR];     //  8704 B  [c][s]
    __shared__ int    xs[SB * NF];         //  1536 B
    __shared__ float  lin_s[SB];           //    64 B

    const int tid = threadIdx.x;
    const int b0  = blockIdx.x * SB;

    if (tid < SB * NF) xs[tid] = x[b0 * NF + tid];
    __syncthreads();

    // linear term (+ blin + b3); overlaps the pipeline
    if (tid < SB) {
        float l = blin[0] + b3[0];
        #pragma unroll
        for (int f = 0; f < NF; ++f) l += Wlin[f * CARDN + xs[tid * NF + f]];
        lin_s[tid] = l;
    }

    // pair decode (tid < NI; NI=276 <= NT=576 so one pair per thread)
    int pi = 0, pj = 0;
    if (tid < NI) {
        int rem = tid, cnt = NF - 1;
        while (rem >= cnt) { rem -= cnt; --cnt; ++pi; }
        pj = pi + 1 + rem;
    }

    // per-thread staged registers: f4 indices v = tid + k*NT, k=0..3 (2304 total)
    float4 st[4];

    // ---- prologue: load + store sample 0 ----
    #pragma unroll
    for (int k = 0; k < 4; ++k) {
        int v = tid + k * NT;
        int r = v / 96, w = v - r * 96;              // w = c*4 + q
        st[k] = *((const float4*)(E + ((size_t)r * CARDN + xs[r]) * (NF * DD)) + w);
    }
    #pragma unroll
    for (int k = 0; k < 4; ++k) {
        int v = tid + k * NT;
        int r = v / 96, w = v - r * 96;
        int c = w >> 2, q = w & 3;
        buf[r * ROW_F4 + c * CH_F4 + q] = st[k];
    }
    __syncthreads();

    // ---- pipelined stages ----
    for (int t = 0; t < SB; ++t) {
        // 1) issue loads for sample t+1 (in flight during compute below)
        if (t + 1 < SB) {
            #pragma unroll
            for (int k = 0; k < 4; ++k) {
                int v = tid + k * NT;
                int r = v / 96, w = v - r * 96;
                st[k] = *((const float4*)(E +
                    ((size_t)r * CARDN + xs[(t + 1) * NF + r]) * (NF * DD)) + w);
            }
        }
        // 2) compute sample t's pair dots from buf[t&1]
        if (tid < NI) {
            const float4* A = &buf[(t & 1) * BUF_F4 + pi * ROW_F4 + pj * CH_F4];
            const float4* C = &buf[(t & 1) * BUF_F4 + pj * ROW_F4 + pi * CH_F4];
            float4 a0 = A[0], a1 = A[1], a2 = A[2], a3 = A[3];
            float4 c0 = C[0], c1 = C[1], c2 = C[2], c3 = C[3];
            float d =
                a0.x*c0.x + a0.y*c0.y + a0.z*c0.z + a0.w*c0.w +
                a1.x*c1.x + a1.y*c1.y + a1.z*c1.z + a1.w*c1.w +
                a2.x*c2.x + a2.y*c2.y + a2.z*c2.z + a2.w*c2.w +
                a3.x*c3.x + a3.y*c3.y + a3.z*c3.z + a3.w*c3.w;
            pairsT[tid * PSTR + t] = d;
        }
        // 3) write sample t+1 into the buffer read two stages ago
        if (t + 1 < SB) {
            #pragma unroll
            for (int k = 0; k < 4; ++k) {
                int v = tid + k * NT;
                int r = v / 96, w = v - r * 96;
                int c = w >> 2, q = w & 3;
                buf[((t + 1) & 1) * BUF_F4 + r * ROW_F4 + c * CH_F4 + q] = st[k];
            }
        }
        __syncthreads();
    }

    // ---- GEMM1: h1[s][c] = relu(pairs[s][:] . W1[:][c] + b1[c]) ----
    if (tid < 512) {
        const int c4 = tid & 31;    // cols c4*4 .. +3
        const int s  = tid >> 5;    // 0..15
        float acc[4] = {};
        #pragma unroll 4
        for (int p = 0; p < NI; ++p) {
            float pr = pairsT[p * PSTR + s];
            float4 w = *(const float4*)(W1 + p * H1N + c4 * 4);
            acc[0] = fmaf(pr, w.x, acc[0]);
            acc[1] = fmaf(pr, w.y, acc[1]);
            acc[2] = fmaf(pr, w.z, acc[2]);
            acc[3] = fmaf(pr, w.w, acc[3]);
        }
        float4 bb = *(const float4*)(b1 + c4 * 4);
        h1T[(c4 * 4 + 0) * PSTR + s] = fmaxf(acc[0] + bb.x, 0.f);
        h1T[(c4 * 4 + 1) * PSTR + s] = fmaxf(acc[1] + bb.y, 0.f);
        h1T[(c4 * 4 + 2) * PSTR + s] = fmaxf(acc[2] + bb.z, 0.f);
        h1T[(c4 * 4 + 3) * PSTR + s] = fmaxf(acc[3] + bb.w, 0.f);
    }
    __syncthreads();

    // ---- GEMM2 (regs) + GEMM3 + linear, shuffle-reduced over 32 lanes ----
    if (tid < 512) {
        const int cl = tid & 31;    // cols cl and cl+32
        const int s  = tid >> 5;    // 0..15
        float a0 = 0.f, a1 = 0.f;
        #pragma unroll 4
        for (int p = 0; p < H1N; ++p) {
            float pr = h1T[p * PSTR + s];
            a0 = fmaf(pr, W2[p * H2N + cl], a0);
            a1 = fmaf(pr, W2[p * H2N + cl + 32], a1);
        }
        float r = fmaxf(a0 + b2[cl],      0.f) * W3[cl]
                + fmaxf(a1 + b2[cl + 32], 0.f) * W3[cl + 32];
        r += __shfl_xor(r, 1);
        r += __shfl_xor(r, 2);
        r += __shfl_xor(r, 4);
        r += __shfl_xor(r, 8);
        r += __shfl_xor(r, 16);
        if (cl == 0) out[b0 + s] = r + lin_s[s];
    }
}

extern "C" void kernel_launch(void* const* d_in, const int* in_sizes, int n_in,
                              void* d_out, int out_size, void* d_ws, size_t ws_size,
                              hipStream_t stream) {
    const int*   x    = (const int*)  d_in[0];
    const float* E    = (const float*)d_in[1];
    const float* Wlin = (const float*)d_in[2];
    const float* blin = (const float*)d_in[3];
    const float* W1   = (const float*)d_in[4];
    const float* b1   = (const float*)d_in[5];
    const float* W2   = (const float*)d_in[6];
    const float* b2   = (const float*)d_in[7];
    const float* W3   = (const float*)d_in[8];
    const float* b3   = (const float*)d_in[9];
    float* out = (float*)d_out;
    (void)d_ws; (void)ws_size; (void)in_sizes; (void)n_in; (void)out_size;

    fanfm_r8_kernel<<<BB / SB, NT, 0, stream>>>(
        x, E, Wlin, blin, W1, b1, W2, b2, W3, b3, out);
}